// Round 3
// baseline (88.083 us; speedup 1.0000x reference)
//
#include <hip/hip_runtime.h>

#define NQ 10
#define NG 4
#define QD 6
#define NBATCH 1024

// 2^10 = 1024 amps; 64 lanes x 16 amps/lane. One WAVE = one REAL COMPONENT
// (re or im) of one circuit (tangent-form layers are real; R10/R13-validated).
// 8192 waves -> 8/SIMD. Init computed once by the even wave, im shipped via
// LDS (R13-validated). Expectations couple re+im partials via 128 B LDS.
// Flat index i: bit p (LSB) <-> wire q = 9-p (wire 0 = MSB, PennyLane order).
// Layout A ONLY: reg bits 0..3 <- amp bits 0..3, lane bits 0..5 <- amp 4..9.
//
// R15: kernel was LDS-PIPE THROUGHPUT bound (~460 ds_swizzle/bpermute per
// wave on the single per-CU LDS pipe shared by 4 SIMDs, ~6cyc each ≈ 37us;
// VALU demand only ~9us). All per-layer cross-lane ops moved to VALU:
//   xor1/xor2  = quad_perm DPP fused v_fmac_dpp (unchanged, ~free)
//   xor4       = row_half_mirror(xor7) mov_dpp + fused quad-mirror(xor3) fmac
//   xor8       = row_half_mirror(xor7) mov_dpp + fused row_mirror(xor15) fmac
//   xor16/32   = v_permlane{16,32}_swap_b32 paired Givens: swap (A,B)->(P,Q)
//                puts partners in the SAME lane => P'=P-t*Q, Q'=Q+t*P with
//                UNIFORM t (no cndmask, no per-lane sign), swap back.
//                4 instr / 2 regs. Expectation sums done in swapped domain
//                (1 fma/pair, x2 after reduce, destructive-last).
// LDS pipe now only: init im-ship (32 ops) + partlds + wave_product (idle).
// tan-form rotations + global scale (R9), CZ sign-bit xor layout-A masks.

// ---------- DPP helpers ----------
template<int CTRL, int RM, int BM, bool BC>
__device__ __forceinline__ float dppmov(float x) {
    return __int_as_float(__builtin_amdgcn_update_dpp(
        0, __float_as_int(x), CTRL, RM, BM, BC));
}
template<int CTRL>
__device__ __forceinline__ float dpp1(float x) { return dppmov<CTRL,0xF,0xF,true>(x); }

template<int PAT>
__device__ __forceinline__ float swz(float x) {
    return __int_as_float(__builtin_amdgcn_ds_swizzle(__float_as_int(x), PAT));
}

// DPP ctrl constants: 0xB1 quad[1,0,3,2]=xor1, 0x4E quad[2,3,0,1]=xor2,
// 0x1B quad[3,2,1,0]=xor3, 0x141 row_half_mirror=xor7, 0x140 row_mirror=xor15.
struct FX1 { static __device__ __forceinline__ float f(float x){ return dpp1<0xB1>(x); } };
struct FX2 { static __device__ __forceinline__ float f(float x){ return dpp1<0x4E>(x); } };
struct FX4 { static __device__ __forceinline__ float f(float x){ return swz<0x101F>(x); } };
struct FX8 { static __device__ __forceinline__ float f(float x){ return swz<0x201F>(x); } };
struct FX16{ static __device__ __forceinline__ float f(float x){ return swz<0x401F>(x); } };
struct FX32{ static __device__ __forceinline__ float f(float x){ return __shfl_xor(x, 32, 64); } };

__device__ __forceinline__ float rlane(float v, int idx) {
    return __int_as_float(__builtin_amdgcn_readlane(__float_as_int(v), idx));
}

// gfx950 cross-row swaps (VALU pipe, 1 instr, modifies both regs in place).
// v_permlane16_swap: vdst rows 1,3 <-> vsrc rows 0,2 (rows = 16 lanes).
// v_permlane32_swap: vdst lanes 32..63 <-> vsrc lanes 0..31.
__device__ __forceinline__ void plswap16(float &a, float &b) {
    asm("v_permlane16_swap_b32 %0, %1" : "+v"(a), "+v"(b));
}
__device__ __forceinline__ void plswap32(float &a, float &b) {
    asm("v_permlane32_swap_b32 %0, %1" : "+v"(a), "+v"(b));
}

// wave-wide sum broadcast (validated R3..R13)
__device__ __forceinline__ float wave_reduce(float x) {
    x += dppmov<0x111,0xF,0xF,true >(x);
    x += dppmov<0x112,0xF,0xF,true >(x);
    x += dppmov<0x114,0xF,0xF,true >(x);
    x += dppmov<0x118,0xF,0xF,true >(x);
    x += dppmov<0x142,0xA,0xF,false>(x);
    x += dppmov<0x143,0xC,0xF,false>(x);
    return __int_as_float(__builtin_amdgcn_readlane(__float_as_int(x), 63));
}

// wave-wide product (R9-validated; once per wave, LDS pipe is idle now)
__device__ __forceinline__ float wave_product(float x) {
    x *= dpp1<0xB1>(x);
    x *= dpp1<0x4E>(x);
    x *= FX4::f(x);
    x *= FX8::f(x);
    x *= FX16::f(x);
    x *= FX32::f(x);
    return x;
}

// (I - t*J) intra-register pair (R9-validated)
template<int M>
__device__ __forceinline__ void intra1(float (&s)[16], float t) {
#pragma unroll
    for (int j = 0; j < 16; ++j)
        if ((j & M) == 0) {
            const int k = j | M;
            float v0 = s[j], v1 = s[k];
            s[j] = fmaf(-t, v1, v0);
            s[k] = fmaf( t, v0, v1);
        }
}

// (I - t*J) cross-lane via single fused DPP (xor1/xor2; sign conv validated)
template<class PF, int LM>
__device__ __forceinline__ void cross1(float (&s)[16], float t, int lane) {
    const float sv = (lane & LM) ? t : -t;
#pragma unroll
    for (int j = 0; j < 16; ++j)
        s[j] = fmaf(PF::f(s[j]), sv, s[j]);
}

// (I - t*J) cross-lane via composed DPP: partner = s[lane ^ (X1^X2)]
// tmp = dpp<C1>(s) (xor X1), fused fmac with dpp<C2> (xor X2). 2 VALU/elem.
template<int C1, int C2, int LM>
__device__ __forceinline__ void cross1_dpp2(float (&s)[16], float t, int lane) {
    const float sv = (lane & LM) ? t : -t;
#pragma unroll
    for (int j = 0; j < 16; ++j) {
        float tmp = dpp1<C1>(s[j]);
        s[j] = fmaf(dpp1<C2>(tmp), sv, s[j]);
    }
}

// (I - t*J) on lane-bit-4 (xor16) via paired permlane16_swap Givens.
// (A,B)->swap->(P,Q): same-lane partners; P'=P-t*Q, Q'=Q+t*P (uniform t,
// matches sv=(lane&16)?t:-t convention); swap back. 4 instr / 2 regs.
__device__ __forceinline__ void cross_pl16(float (&s)[16], float t) {
#pragma unroll
    for (int j = 0; j < 16; j += 2) {
        float P = s[j], Q = s[j + 1];
        plswap16(P, Q);
        float Pn = fmaf(-t, Q, P);
        float Qn = fmaf( t, P, Q);
        plswap16(Pn, Qn);
        s[j] = Pn; s[j + 1] = Qn;
    }
}

// Same for lane-bit-5 (xor32) via permlane32_swap.
__device__ __forceinline__ void cross_pl32(float (&s)[16], float t) {
#pragma unroll
    for (int j = 0; j < 16; j += 2) {
        float P = s[j], Q = s[j + 1];
        plswap32(P, Q);
        float Pn = fmaf(-t, Q, P);
        float Qn = fmaf( t, P, Q);
        plswap32(Pn, Qn);
        s[j] = Pn; s[j + 1] = Qn;
    }
}

template<class PF>
__device__ __forceinline__ float cross_exp1(const float (&s)[16]) {
    float a = 0.f;
#pragma unroll
    for (int j = 0; j < 16; ++j)
        a = fmaf(PF::f(s[j]), s[j], a);
    return a;
}

// expectation with composed-DPP partner (xor4/xor8). 2 VALU/elem.
template<int C1, int C2>
__device__ __forceinline__ float cross_exp_dpp2(const float (&s)[16]) {
    float a = 0.f;
#pragma unroll
    for (int j = 0; j < 16; ++j) {
        float tmp = dpp1<C1>(s[j]);
        a = fmaf(dpp1<C2>(tmp), s[j], a);
    }
    return a;
}

template<int M>
__device__ __forceinline__ float intra_exp1(const float (&s)[16]) {
    float a = 0.f;
#pragma unroll
    for (int j = 0; j < 16; ++j)
        a += s[j] * s[j ^ M];
    return a;
}

__global__ __launch_bounds__(256, 2) void qsim_kernel(
    const float* __restrict__ noise,     // (NBATCH, NQ)
    const float* __restrict__ qp,        // (NG, QD, NQ)
    float* __restrict__ out)             // (NBATCH, NG*NQ)
{
    __shared__ float ship[2][1024];      // im half of init state per circuit
    __shared__ float partlds[2][16];     // re-wave expectation partials

    const int wave = threadIdx.x >> 6;
    const int lane = threadIdx.x & 63;
    const int pc   = wave >> 1;                       // circuit within block
    const int comp = wave & 1;                        // 0 = re, 1 = im
    const int g    = blockIdx.x & 3;                  // block-uniform
    const int b    = (blockIdx.x >> 2) * 2 + pc;      // batch index

    // ---- weights: lane-parallel sincos once; t = tan, scale2 = prod(c)^2 ----
    float wt, scale2;
    {
        const int widx = (lane < QD * NQ) ? lane : 0;
        float sv, cv;
        __sincosf(0.5f * qp[g * (QD * NQ) + widx], &sv, &cv);
        wt = sv / cv;
        float cvc = (lane < QD * NQ) ? cv : 1.0f;
        float p = wave_product(cvc);
        scale2 = p * p;
    }

    // ---- init: even wave computes complex product state, ships im via LDS ----
    float s[16];
    if (comp == 0) {
        float nc[NQ], ns[NQ];
#pragma unroll
        for (int q = 0; q < NQ; ++q)
            __sincosf(0.5f * noise[b * NQ + q], &ns[q], &nc[q]);

        auto facr = [&](int q, int bit) { return bit ? nc[q]*ns[q] : nc[q]*nc[q]; };
        auto faci = [&](int q, int bit) { return bit ? -nc[q]*ns[q] : -ns[q]*ns[q]; };

        float hr = 1.f, hi = 0.f;
#pragma unroll
        for (int p = 4; p <= 9; ++p) {
            const int q = NQ - 1 - p, bit = (lane >> (p - 4)) & 1;
            float fr = facr(q, bit), fi = faci(q, bit);
            float tr = hr * fr - hi * fi;
            float ti = hr * fi + hi * fr;
            hr = tr; hi = ti;
        }
        float t01r[4], t01i[4], t23r[4], t23i[4];
#pragma unroll
        for (int a = 0; a < 4; ++a) {
            float f9r = facr(9, a & 1), f9i = faci(9, a & 1);
            float f8r = facr(8, (a >> 1) & 1), f8i = faci(8, (a >> 1) & 1);
            t01r[a] = f9r * f8r - f9i * f8i;
            t01i[a] = f9r * f8i + f9i * f8r;
            float f7r = facr(7, a & 1), f7i = faci(7, a & 1);
            float f6r = facr(6, (a >> 1) & 1), f6i = faci(6, (a >> 1) & 1);
            t23r[a] = f7r * f6r - f7i * f6i;
            t23i[a] = f7r * f6i + f7i * f6r;
        }
        float prer[4], prei[4];
#pragma unroll
        for (int a = 0; a < 4; ++a) {
            prer[a] = hr * t01r[a] - hi * t01i[a];
            prei[a] = hr * t01i[a] + hi * t01r[a];
        }
#pragma unroll
        for (int j = 0; j < 16; ++j) {
            s[j] = prer[j & 3] * t23r[j >> 2] - prei[j & 3] * t23i[j >> 2];
            float ii = prer[j & 3] * t23i[j >> 2] + prei[j & 3] * t23r[j >> 2];
            ship[pc][j * 64 + lane] = ii;   // conflict-free (stride-1 per lane)
        }
    }
    __syncthreads();
    if (comp == 1) {
#pragma unroll
        for (int j = 0; j < 16; ++j) s[j] = ship[pc][j * 64 + lane];
    }

    // ---- CZ sign masks, layout A (R9/R12-validated parity decomposition) ----
    unsigned aE, aO;
    {
        unsigned parA = (unsigned)(__popc(lane & (lane >> 1)) & 1) << 31;
        aE = parA;                                     // j < 8
        aO = parA ^ ((unsigned)(lane & 1) << 31);      // j >= 8 (pair j3,l0)
    }
    auto czA = [&](float (&v)[16]) {
#pragma unroll
        for (int j = 0; j < 16; ++j) {
            const bool jp = (__popc(j & (j >> 1)) & 1) != 0;         // compile-time
            const unsigned base = (j & 8) ? aO : aE;
            const unsigned m = jp ? (base ^ 0x80000000u) : base;
            v[j] = __uint_as_float(__float_as_uint(v[j]) ^ m);
        }
    };

    // ---- QD layers: all cross-lane on VALU pipe (R15); RY on distinct wires
    // commute exactly, so order is free. ----
#pragma unroll 1
    for (int l = 0; l < QD; ++l) {
        float t[NQ];
#pragma unroll
        for (int q = 0; q < NQ; ++q) t[q] = rlane(wt, l * NQ + q);

        cross_pl32(s, t[0]);                        // wire 0 (lane bit 5) [permlane32]
        cross_pl16(s, t[1]);                        // wire 1 (lane bit 4) [permlane16]
        cross1_dpp2<0x141,0x140, 8>(s, t[2], lane); // wire 2 (xor8 = 15o7) [DPP]
        cross1_dpp2<0x141,0x1B,  4>(s, t[3], lane); // wire 3 (xor4 = 3o7)  [DPP]
        intra1<1>(s, t[9]);                         // wires 9..6 (reg bits)
        intra1<2>(s, t[8]);
        intra1<4>(s, t[7]);
        intra1<8>(s, t[6]);
        cross1<FX1, 1>(s, t[5], lane);              // wire 5 (lane bit 0)  [DPP]
        cross1<FX2, 2>(s, t[4], lane);              // wire 4 (lane bit 1)  [DPP]
        czA(s);
    }

    // ---- expectations: this component's partial sums ----
    float myp = 0.f;
    {
        float e9 = wave_reduce(intra_exp1<1>(s));
        float e8 = wave_reduce(intra_exp1<2>(s));
        float e7 = wave_reduce(intra_exp1<4>(s));
        float e6 = wave_reduce(intra_exp1<8>(s));
        float e5 = wave_reduce(cross_exp1<FX1>(s));
        float e4 = wave_reduce(cross_exp1<FX2>(s));
        float e3 = wave_reduce(cross_exp_dpp2<0x141,0x1B >(s));
        float e2 = wave_reduce(cross_exp_dpp2<0x141,0x140>(s));
        // xor16 & xor32 sums in the swapped domain (destructive-last; s dead
        // after). Sum over lanes of P*Q = half the true pair-sum -> x2.
        float p16 = 0.f, p32 = 0.f;
#pragma unroll
        for (int j = 0; j < 16; j += 2) {
            float P = s[j], Q = s[j + 1];
            plswap16(P, Q);
            p16 = fmaf(P, Q, p16);
            plswap32(P, Q);
            p32 = fmaf(P, Q, p32);
        }
        float e1 = 2.0f * wave_reduce(p16);
        float e0 = 2.0f * wave_reduce(p32);
        myp = (lane == 0) ? e0 : myp;
        myp = (lane == 1) ? e1 : myp;
        myp = (lane == 2) ? e2 : myp;
        myp = (lane == 3) ? e3 : myp;
        myp = (lane == 4) ? e4 : myp;
        myp = (lane == 5) ? e5 : myp;
        myp = (lane == 6) ? e6 : myp;
        myp = (lane == 7) ? e7 : myp;
        myp = (lane == 8) ? e8 : myp;
        myp = (lane == 9) ? e9 : myp;
    }

    // ---- couple re+im partials via LDS; im wave stores (R13-validated) ----
    if (comp == 0 && lane < NQ) partlds[pc][lane] = myp;
    __syncthreads();
    if (comp == 1 && lane < NQ)
        out[b * (NG * NQ) + g * NQ + lane] = (myp + partlds[pc][lane]) * scale2;
}

extern "C" void kernel_launch(void* const* d_in, const int* in_sizes, int n_in,
                              void* d_out, int out_size, void* d_ws, size_t ws_size,
                              hipStream_t stream) {
    const float* noise = (const float*)d_in[0];   // (1024, 10) float32
    const float* qp    = (const float*)d_in[1];   // (4, 6, 10) float32
    float* out = (float*)d_out;                   // (1024, 40) float32

    const int nblocks = (NBATCH * NG) / 2;        // 2048 blocks x 4 waves
    qsim_kernel<<<nblocks, 256, 0, stream>>>(noise, qp, out);
}

// Round 4
// 85.108 us; speedup vs baseline: 1.0350x; 1.0350x over previous
//
#include <hip/hip_runtime.h>

#define NQ 10
#define NG 4
#define QD 6
#define NBATCH 1024

// 2^10 = 1024 amps; 64 lanes x 16 amps/lane. One WAVE = one REAL COMPONENT
// (re or im) of one circuit (tangent-form layers are real; R10/R13-validated).
// 8192 waves -> 8/SIMD. R16: BOTH waves compute the full complex init
// independently (im wave formerly idled at a barrier during re's init; the
// LDS ship + first barrier are deleted; LDS = 128 B partlds only).
// Flat index i: bit p (LSB) <-> wire q = 9-p (wire 0 = MSB, PennyLane order).
// Layout A ONLY: reg bits 0..3 <- amp bits 0..3, lane bits 0..5 <- amp 4..9.
//
// R16 PIPE BALANCE (post-mortem of R15): all-LDS (R14) = 40us (LDS pipe
// ~37us busy, VALU 9us idle-ish); all-VALU (R15) = 40us (VALU ~30us busy,
// LDS idle; cross-lane VALU ops ~4cyc not 2). Neither pipe alone wins ->
// split the 6 cross wires across BOTH pipes so they overlap across waves:
//   xor1/xor2  = quad_perm DPP fused v_fmac_dpp                 [VALU]
//   xor4/xor8  = row_half_mirror + fused mirror fmac (R15-pass) [VALU]
//   xor16      = ds_swizzle BitMode 0x401F (R12/R14-validated)  [LDS]
//   xor32      = __shfl_xor -> ds_bpermute (R14-validated)      [LDS]
// tan-form rotations + global scale (R9), CZ sign-bit xor layout-A masks.

// ---------- DPP helpers ----------
template<int CTRL, int RM, int BM, bool BC>
__device__ __forceinline__ float dppmov(float x) {
    return __int_as_float(__builtin_amdgcn_update_dpp(
        0, __float_as_int(x), CTRL, RM, BM, BC));
}
template<int CTRL>
__device__ __forceinline__ float dpp1(float x) { return dppmov<CTRL,0xF,0xF,true>(x); }

template<int PAT>
__device__ __forceinline__ float swz(float x) {
    return __int_as_float(__builtin_amdgcn_ds_swizzle(__float_as_int(x), PAT));
}

// DPP ctrl constants: 0xB1 quad[1,0,3,2]=xor1, 0x4E quad[2,3,0,1]=xor2,
// 0x1B quad[3,2,1,0]=xor3, 0x141 row_half_mirror=xor7, 0x140 row_mirror=xor15.
struct FX1 { static __device__ __forceinline__ float f(float x){ return dpp1<0xB1>(x); } };
struct FX2 { static __device__ __forceinline__ float f(float x){ return dpp1<0x4E>(x); } };
struct FX4 { static __device__ __forceinline__ float f(float x){ return swz<0x101F>(x); } };
struct FX8 { static __device__ __forceinline__ float f(float x){ return swz<0x201F>(x); } };
struct FX16{ static __device__ __forceinline__ float f(float x){ return swz<0x401F>(x); } };
struct FX32{ static __device__ __forceinline__ float f(float x){ return __shfl_xor(x, 32, 64); } };

__device__ __forceinline__ float rlane(float v, int idx) {
    return __int_as_float(__builtin_amdgcn_readlane(__float_as_int(v), idx));
}

// wave-wide sum broadcast (validated R3..R13)
__device__ __forceinline__ float wave_reduce(float x) {
    x += dppmov<0x111,0xF,0xF,true >(x);
    x += dppmov<0x112,0xF,0xF,true >(x);
    x += dppmov<0x114,0xF,0xF,true >(x);
    x += dppmov<0x118,0xF,0xF,true >(x);
    x += dppmov<0x142,0xA,0xF,false>(x);
    x += dppmov<0x143,0xC,0xF,false>(x);
    return __int_as_float(__builtin_amdgcn_readlane(__float_as_int(x), 63));
}

// wave-wide product (R9-validated; once per wave)
__device__ __forceinline__ float wave_product(float x) {
    x *= dpp1<0xB1>(x);
    x *= dpp1<0x4E>(x);
    x *= FX4::f(x);
    x *= FX8::f(x);
    x *= FX16::f(x);
    x *= FX32::f(x);
    return x;
}

// (I - t*J) intra-register pair (R9-validated)
template<int M>
__device__ __forceinline__ void intra1(float (&s)[16], float t) {
#pragma unroll
    for (int j = 0; j < 16; ++j)
        if ((j & M) == 0) {
            const int k = j | M;
            float v0 = s[j], v1 = s[k];
            s[j] = fmaf(-t, v1, v0);
            s[k] = fmaf( t, v0, v1);
        }
}

// (I - t*J) cross-lane via fetch+fma (xor1/xor2 fused DPP; xor16/32 LDS pipe)
template<class PF, int LM>
__device__ __forceinline__ void cross1(float (&s)[16], float t, int lane) {
    const float sv = (lane & LM) ? t : -t;
#pragma unroll
    for (int j = 0; j < 16; ++j)
        s[j] = fmaf(PF::f(s[j]), sv, s[j]);
}

// (I - t*J) cross-lane via composed DPP: partner = s[lane ^ (X1^X2)]
// tmp = dpp<C1>(s) (xor X1), fused fmac with dpp<C2> (xor X2). 2 VALU/elem.
// (R15-pass-validated for xor4 = 3o7, xor8 = 15o7.)
template<int C1, int C2, int LM>
__device__ __forceinline__ void cross1_dpp2(float (&s)[16], float t, int lane) {
    const float sv = (lane & LM) ? t : -t;
#pragma unroll
    for (int j = 0; j < 16; ++j) {
        float tmp = dpp1<C1>(s[j]);
        s[j] = fmaf(dpp1<C2>(tmp), sv, s[j]);
    }
}

template<class PF>
__device__ __forceinline__ float cross_exp1(const float (&s)[16]) {
    float a = 0.f;
#pragma unroll
    for (int j = 0; j < 16; ++j)
        a = fmaf(PF::f(s[j]), s[j], a);
    return a;
}

// expectation with composed-DPP partner (xor4/xor8). 2 VALU/elem.
template<int C1, int C2>
__device__ __forceinline__ float cross_exp_dpp2(const float (&s)[16]) {
    float a = 0.f;
#pragma unroll
    for (int j = 0; j < 16; ++j) {
        float tmp = dpp1<C1>(s[j]);
        a = fmaf(dpp1<C2>(tmp), s[j], a);
    }
    return a;
}

template<int M>
__device__ __forceinline__ float intra_exp1(const float (&s)[16]) {
    float a = 0.f;
#pragma unroll
    for (int j = 0; j < 16; ++j)
        a += s[j] * s[j ^ M];
    return a;
}

__global__ __launch_bounds__(256, 2) void qsim_kernel(
    const float* __restrict__ noise,     // (NBATCH, NQ)
    const float* __restrict__ qp,        // (NG, QD, NQ)
    float* __restrict__ out)             // (NBATCH, NG*NQ)
{
    __shared__ float partlds[2][16];     // re-wave expectation partials only

    const int wave = threadIdx.x >> 6;
    const int lane = threadIdx.x & 63;
    const int pc   = wave >> 1;                       // circuit within block
    const int comp = wave & 1;                        // 0 = re, 1 = im
    const int g    = blockIdx.x & 3;                  // block-uniform
    const int b    = (blockIdx.x >> 2) * 2 + pc;      // batch index

    // ---- weights: lane-parallel sincos once; t = tan, scale2 = prod(c)^2 ----
    float wt, scale2;
    {
        const int widx = (lane < QD * NQ) ? lane : 0;
        float sv, cv;
        __sincosf(0.5f * qp[g * (QD * NQ) + widx], &sv, &cv);
        wt = sv / cv;
        float cvc = (lane < QD * NQ) ? cv : 1.0f;
        float p = wave_product(cvc);
        scale2 = p * p;
    }

    // ---- init: BOTH waves compute the complex product state (R16: the im
    // wave formerly idled at a barrier for exactly this long; no LDS ship) ----
    float s[16];
    {
        float nc[NQ], ns[NQ];
#pragma unroll
        for (int q = 0; q < NQ; ++q)
            __sincosf(0.5f * noise[b * NQ + q], &ns[q], &nc[q]);

        auto facr = [&](int q, int bit) { return bit ? nc[q]*ns[q] : nc[q]*nc[q]; };
        auto faci = [&](int q, int bit) { return bit ? -nc[q]*ns[q] : -ns[q]*ns[q]; };

        float hr = 1.f, hi = 0.f;
#pragma unroll
        for (int p = 4; p <= 9; ++p) {
            const int q = NQ - 1 - p, bit = (lane >> (p - 4)) & 1;
            float fr = facr(q, bit), fi = faci(q, bit);
            float tr = hr * fr - hi * fi;
            float ti = hr * fi + hi * fr;
            hr = tr; hi = ti;
        }
        float t01r[4], t01i[4], t23r[4], t23i[4];
#pragma unroll
        for (int a = 0; a < 4; ++a) {
            float f9r = facr(9, a & 1), f9i = faci(9, a & 1);
            float f8r = facr(8, (a >> 1) & 1), f8i = faci(8, (a >> 1) & 1);
            t01r[a] = f9r * f8r - f9i * f8i;
            t01i[a] = f9r * f8i + f9i * f8r;
            float f7r = facr(7, a & 1), f7i = faci(7, a & 1);
            float f6r = facr(6, (a >> 1) & 1), f6i = faci(6, (a >> 1) & 1);
            t23r[a] = f7r * f6r - f7i * f6i;
            t23i[a] = f7r * f6i + f7i * f6r;
        }
        float prer[4], prei[4];
#pragma unroll
        for (int a = 0; a < 4; ++a) {
            prer[a] = hr * t01r[a] - hi * t01i[a];
            prei[a] = hr * t01i[a] + hi * t01r[a];
        }
#pragma unroll
        for (int j = 0; j < 16; ++j) {
            const float re = prer[j & 3] * t23r[j >> 2] - prei[j & 3] * t23i[j >> 2];
            const float im = prer[j & 3] * t23i[j >> 2] + prei[j & 3] * t23r[j >> 2];
            s[j] = (comp == 0) ? re : im;    // comp is wave-uniform
        }
    }

    // ---- CZ sign masks, layout A (R9/R12-validated parity decomposition) ----
    unsigned aE, aO;
    {
        unsigned parA = (unsigned)(__popc(lane & (lane >> 1)) & 1) << 31;
        aE = parA;                                     // j < 8
        aO = parA ^ ((unsigned)(lane & 1) << 31);      // j >= 8 (pair j3,l0)
    }
    auto czA = [&](float (&v)[16]) {
#pragma unroll
        for (int j = 0; j < 16; ++j) {
            const bool jp = (__popc(j & (j >> 1)) & 1) != 0;         // compile-time
            const unsigned base = (j & 8) ? aO : aE;
            const unsigned m = jp ? (base ^ 0x80000000u) : base;
            v[j] = __uint_as_float(__float_as_uint(v[j]) ^ m);
        }
    };

    // ---- QD layers: wires 0,1 on LDS pipe (issue early, overlap with VALU
    // wires of other waves); wires 2..5 DPP; 6..9 intra. RY on distinct
    // wires commute exactly, so order is free. ----
#pragma unroll 1
    for (int l = 0; l < QD; ++l) {
        float t[NQ];
#pragma unroll
        for (int q = 0; q < NQ; ++q) t[q] = rlane(wt, l * NQ + q);

        cross1<FX32,32>(s, t[0], lane);             // wire 0 (lane bit 5) [LDS]
        cross1<FX16,16>(s, t[1], lane);             // wire 1 (lane bit 4) [LDS]
        cross1_dpp2<0x141,0x140, 8>(s, t[2], lane); // wire 2 (xor8 = 15o7) [DPP]
        cross1_dpp2<0x141,0x1B,  4>(s, t[3], lane); // wire 3 (xor4 = 3o7)  [DPP]
        intra1<1>(s, t[9]);                         // wires 9..6 (reg bits)
        intra1<2>(s, t[8]);
        intra1<4>(s, t[7]);
        intra1<8>(s, t[6]);
        cross1<FX1, 1>(s, t[5], lane);              // wire 5 (lane bit 0)  [DPP]
        cross1<FX2, 2>(s, t[4], lane);              // wire 4 (lane bit 1)  [DPP]
        czA(s);
    }

    // ---- expectations: this component's partial sums (LDS-users first) ----
    float myp = 0.f;
    {
        float p0 = cross_exp1<FX32>(s);             // [LDS]
        float p1 = cross_exp1<FX16>(s);             // [LDS]
        float p2 = cross_exp_dpp2<0x141,0x140>(s);
        float p3 = cross_exp_dpp2<0x141,0x1B >(s);
        float p4 = cross_exp1<FX2>(s);
        float p5 = cross_exp1<FX1>(s);
        float p6 = intra_exp1<8>(s);
        float p7 = intra_exp1<4>(s);
        float p8 = intra_exp1<2>(s);
        float p9 = intra_exp1<1>(s);
        float e0 = wave_reduce(p0);
        float e1 = wave_reduce(p1);
        float e2 = wave_reduce(p2);
        float e3 = wave_reduce(p3);
        float e4 = wave_reduce(p4);
        float e5 = wave_reduce(p5);
        float e6 = wave_reduce(p6);
        float e7 = wave_reduce(p7);
        float e8 = wave_reduce(p8);
        float e9 = wave_reduce(p9);
        myp = (lane == 0) ? e0 : myp;
        myp = (lane == 1) ? e1 : myp;
        myp = (lane == 2) ? e2 : myp;
        myp = (lane == 3) ? e3 : myp;
        myp = (lane == 4) ? e4 : myp;
        myp = (lane == 5) ? e5 : myp;
        myp = (lane == 6) ? e6 : myp;
        myp = (lane == 7) ? e7 : myp;
        myp = (lane == 8) ? e8 : myp;
        myp = (lane == 9) ? e9 : myp;
    }

    // ---- couple re+im partials via LDS; im wave stores (R13-validated) ----
    if (comp == 0 && lane < NQ) partlds[pc][lane] = myp;
    __syncthreads();
    if (comp == 1 && lane < NQ)
        out[b * (NG * NQ) + g * NQ + lane] = (myp + partlds[pc][lane]) * scale2;
}

extern "C" void kernel_launch(void* const* d_in, const int* in_sizes, int n_in,
                              void* d_out, int out_size, void* d_ws, size_t ws_size,
                              hipStream_t stream) {
    const float* noise = (const float*)d_in[0];   // (1024, 10) float32
    const float* qp    = (const float*)d_in[1];   // (4, 6, 10) float32
    float* out = (float*)d_out;                   // (1024, 40) float32

    const int nblocks = (NBATCH * NG) / 2;        // 2048 blocks x 4 waves
    qsim_kernel<<<nblocks, 256, 0, stream>>>(noise, qp, out);
}

// Round 11
// 84.375 us; speedup vs baseline: 1.0439x; 1.0087x over previous
//
#include <hip/hip_runtime.h>

#define NQ 10
#define NG 4
#define QD 6
#define NBATCH 1024

// R18: merged ONE WAVE = ONE FULL COMPLEX CIRCUIT (sre[16]+sim[16]) with
// ZERO new primitives — bisection of R17's correctness failure.
// R17 (merged + inline-asm permlane + launch_bounds(256,4)) FAILED absmax
// 1.55; its components were individually validated in R15/R16, so the
// suspects are (a) raw-asm v_permlane*_swap hazards invisible to the
// compiler's hazard recognizer under R17's denser schedule, (b) the 128-VGPR
// cap forcing spills around opaque asm. R18 removes both: every cross-lane
// op is the R16-validated builtin path (ds_swizzle / shfl_xor / DPP), no
// inline asm anywhere, launch_bounds back to (256,2).
// Delta vs R16 (passed, 0.0039): merged wave structure only — init ONCE,
// wt/scale2 once, 10 merged reduces (not 20), no __shared__, no barriers.
// 4096 waves = 1024 blocks x 4 waves; block = one sample, wave = generator.
// Flat index i: bit p (LSB) <-> wire q = 9-p (wire 0 = MSB, PennyLane order).
// Layout A: reg bits 0..3 <- amp bits 0..3, lane bits 0..5 <- amp 4..9.
//   xor1/xor2  = quad_perm fused v_fmac_dpp              [VALU DPP]
//   xor4/xor8  = row_half_mirror + fused mirror fmac     [VALU DPP, R15/R16]
//   xor16      = ds_swizzle BitMode 0x401F               [LDS, R12/R14/R16]
//   xor32      = __shfl_xor -> ds_bpermute               [LDS, R14/R16]
// tan-form rotations + global scale (R9), CZ sign-bit xor layout-A masks.

// ---------- DPP helpers ----------
template<int CTRL, int RM, int BM, bool BC>
__device__ __forceinline__ float dppmov(float x) {
    return __int_as_float(__builtin_amdgcn_update_dpp(
        0, __float_as_int(x), CTRL, RM, BM, BC));
}
template<int CTRL>
__device__ __forceinline__ float dpp1(float x) { return dppmov<CTRL,0xF,0xF,true>(x); }

template<int PAT>
__device__ __forceinline__ float swz(float x) {
    return __int_as_float(__builtin_amdgcn_ds_swizzle(__float_as_int(x), PAT));
}

// DPP ctrl: 0xB1 quad[1,0,3,2]=xor1, 0x4E quad[2,3,0,1]=xor2,
// 0x1B quad[3,2,1,0]=xor3, 0x141 row_half_mirror=xor7, 0x140 row_mirror=xor15.
struct FX1 { static __device__ __forceinline__ float f(float x){ return dpp1<0xB1>(x); } };
struct FX2 { static __device__ __forceinline__ float f(float x){ return dpp1<0x4E>(x); } };
struct FX4 { static __device__ __forceinline__ float f(float x){ return swz<0x101F>(x); } };
struct FX8 { static __device__ __forceinline__ float f(float x){ return swz<0x201F>(x); } };
struct FX16{ static __device__ __forceinline__ float f(float x){ return swz<0x401F>(x); } };
struct FX32{ static __device__ __forceinline__ float f(float x){ return __shfl_xor(x, 32, 64); } };

__device__ __forceinline__ float rlane(float v, int idx) {
    return __int_as_float(__builtin_amdgcn_readlane(__float_as_int(v), idx));
}

// wave-wide sum broadcast (validated R3..R16)
__device__ __forceinline__ float wave_reduce(float x) {
    x += dppmov<0x111,0xF,0xF,true >(x);
    x += dppmov<0x112,0xF,0xF,true >(x);
    x += dppmov<0x114,0xF,0xF,true >(x);
    x += dppmov<0x118,0xF,0xF,true >(x);
    x += dppmov<0x142,0xA,0xF,false>(x);
    x += dppmov<0x143,0xC,0xF,false>(x);
    return __int_as_float(__builtin_amdgcn_readlane(__float_as_int(x), 63));
}

// wave-wide product (R9-validated; once per wave)
__device__ __forceinline__ float wave_product(float x) {
    x *= dpp1<0xB1>(x);
    x *= dpp1<0x4E>(x);
    x *= FX4::f(x);
    x *= FX8::f(x);
    x *= FX16::f(x);
    x *= FX32::f(x);
    return x;
}

// (I - t*J) intra-register pair (R9-validated)
template<int M>
__device__ __forceinline__ void intra1(float (&s)[16], float t) {
#pragma unroll
    for (int j = 0; j < 16; ++j)
        if ((j & M) == 0) {
            const int k = j | M;
            float v0 = s[j], v1 = s[k];
            s[j] = fmaf(-t, v1, v0);
            s[k] = fmaf( t, v0, v1);
        }
}

// (I - t*J) cross-lane via fetch+fma (xor1/xor2 fused DPP; xor16/32 LDS pipe)
template<class PF, int LM>
__device__ __forceinline__ void cross1(float (&s)[16], float t, int lane) {
    const float sv = (lane & LM) ? t : -t;
#pragma unroll
    for (int j = 0; j < 16; ++j)
        s[j] = fmaf(PF::f(s[j]), sv, s[j]);
}

// (I - t*J) cross-lane via composed DPP: partner = s[lane ^ (X1^X2)]
// (R15/R16-validated for xor4 = 3o7, xor8 = 15o7.)
template<int C1, int C2, int LM>
__device__ __forceinline__ void cross1_dpp2(float (&s)[16], float t, int lane) {
    const float sv = (lane & LM) ? t : -t;
#pragma unroll
    for (int j = 0; j < 16; ++j) {
        float tmp = dpp1<C1>(s[j]);
        s[j] = fmaf(dpp1<C2>(tmp), sv, s[j]);
    }
}

template<class PF>
__device__ __forceinline__ float cross_exp1(const float (&s)[16]) {
    float a = 0.f;
#pragma unroll
    for (int j = 0; j < 16; ++j)
        a = fmaf(PF::f(s[j]), s[j], a);
    return a;
}

// expectation with composed-DPP partner (xor4/xor8). (R15/R16-validated)
template<int C1, int C2>
__device__ __forceinline__ float cross_exp_dpp2(const float (&s)[16]) {
    float a = 0.f;
#pragma unroll
    for (int j = 0; j < 16; ++j) {
        float tmp = dpp1<C1>(s[j]);
        a = fmaf(dpp1<C2>(tmp), s[j], a);
    }
    return a;
}

template<int M>
__device__ __forceinline__ float intra_exp1(const float (&s)[16]) {
    float a = 0.f;
#pragma unroll
    for (int j = 0; j < 16; ++j)
        a += s[j] * s[j ^ M];
    return a;
}

__global__ __launch_bounds__(256, 2) void qsim_kernel(
    const float* __restrict__ noise,     // (NBATCH, NQ)
    const float* __restrict__ qp,        // (NG, QD, NQ)
    float* __restrict__ out)             // (NBATCH, NG*NQ)
{
    const int wave = threadIdx.x >> 6;
    const int lane = threadIdx.x & 63;
    const int cid  = blockIdx.x * 4 + wave;   // 4096 circuits = 1024 b x 4 g
    const int g    = cid & 3;                 // = wave (wave-uniform)
    const int b    = cid >> 2;                // = blockIdx.x (shared in block)

    // ---- weights: lane-parallel sincos once; t = tan, scale2 = prod(c)^2 ----
    float wt, scale2;
    {
        const int widx = (lane < QD * NQ) ? lane : 0;
        float sv, cv;
        __sincosf(0.5f * qp[g * (QD * NQ) + widx], &sv, &cv);
        wt = sv / cv;
        float cvc = (lane < QD * NQ) ? cv : 1.0f;
        float p = wave_product(cvc);
        scale2 = p * p;
    }

    // ---- init: complex product state, ONCE per circuit, both comps in regs ----
    float sre[16], sim[16];
    {
        float nc[NQ], ns[NQ];
#pragma unroll
        for (int q = 0; q < NQ; ++q)
            __sincosf(0.5f * noise[b * NQ + q], &ns[q], &nc[q]);

        auto facr = [&](int q, int bit) { return bit ? nc[q]*ns[q] : nc[q]*nc[q]; };
        auto faci = [&](int q, int bit) { return bit ? -nc[q]*ns[q] : -ns[q]*ns[q]; };

        float hr = 1.f, hi = 0.f;
#pragma unroll
        for (int p = 4; p <= 9; ++p) {
            const int q = NQ - 1 - p, bit = (lane >> (p - 4)) & 1;
            float fr = facr(q, bit), fi = faci(q, bit);
            float tr = hr * fr - hi * fi;
            float ti = hr * fi + hi * fr;
            hr = tr; hi = ti;
        }
        float t01r[4], t01i[4], t23r[4], t23i[4];
#pragma unroll
        for (int a = 0; a < 4; ++a) {
            float f9r = facr(9, a & 1), f9i = faci(9, a & 1);
            float f8r = facr(8, (a >> 1) & 1), f8i = faci(8, (a >> 1) & 1);
            t01r[a] = f9r * f8r - f9i * f8i;
            t01i[a] = f9r * f8i + f9i * f8r;
            float f7r = facr(7, a & 1), f7i = faci(7, a & 1);
            float f6r = facr(6, (a >> 1) & 1), f6i = faci(6, (a >> 1) & 1);
            t23r[a] = f7r * f6r - f7i * f6i;
            t23i[a] = f7r * f6i + f7i * f6r;
        }
        float prer[4], prei[4];
#pragma unroll
        for (int a = 0; a < 4; ++a) {
            prer[a] = hr * t01r[a] - hi * t01i[a];
            prei[a] = hr * t01i[a] + hi * t01r[a];
        }
#pragma unroll
        for (int j = 0; j < 16; ++j) {
            sre[j] = prer[j & 3] * t23r[j >> 2] - prei[j & 3] * t23i[j >> 2];
            sim[j] = prer[j & 3] * t23i[j >> 2] + prei[j & 3] * t23r[j >> 2];
        }
    }

    // ---- CZ sign masks, layout A (R9/R12-validated parity decomposition) ----
    unsigned aE, aO;
    {
        unsigned parA = (unsigned)(__popc(lane & (lane >> 1)) & 1) << 31;
        aE = parA;                                     // j < 8
        aO = parA ^ ((unsigned)(lane & 1) << 31);      // j >= 8 (pair j3,l0)
    }
    auto czA = [&](float (&v)[16]) {
#pragma unroll
        for (int j = 0; j < 16; ++j) {
            const bool jp = (__popc(j & (j >> 1)) & 1) != 0;         // compile-time
            const unsigned base = (j & 8) ? aO : aE;
            const unsigned m = jp ? (base ^ 0x80000000u) : base;
            v[j] = __uint_as_float(__float_as_uint(v[j]) ^ m);
        }
    };

    // ---- QD layers: R16-validated per-component path applied to BOTH comps;
    // LDS-pipe wires first so swizzles issue early; RY on distinct wires
    // commute exactly, so order is free. ----
#pragma unroll 1
    for (int l = 0; l < QD; ++l) {
        float t[NQ];
#pragma unroll
        for (int q = 0; q < NQ; ++q) t[q] = rlane(wt, l * NQ + q);

        cross1<FX32,32>(sre, t[0], lane);            // wire 0 (lane bit 5) [LDS]
        cross1<FX32,32>(sim, t[0], lane);
        cross1<FX16,16>(sre, t[1], lane);            // wire 1 (lane bit 4) [LDS]
        cross1<FX16,16>(sim, t[1], lane);
        cross1_dpp2<0x141,0x140, 8>(sre, t[2], lane); // wire 2 (xor8) [DPP]
        cross1_dpp2<0x141,0x140, 8>(sim, t[2], lane);
        cross1_dpp2<0x141,0x1B,  4>(sre, t[3], lane); // wire 3 (xor4) [DPP]
        cross1_dpp2<0x141,0x1B,  4>(sim, t[3], lane);
        intra1<1>(sre, t[9]);  intra1<1>(sim, t[9]); // wires 9..6 (reg bits)
        intra1<2>(sre, t[8]);  intra1<2>(sim, t[8]);
        intra1<4>(sre, t[7]);  intra1<4>(sim, t[7]);
        intra1<8>(sre, t[6]);  intra1<8>(sim, t[6]);
        cross1<FX1, 1>(sre, t[5], lane);             // wire 5 (lane bit 0) [DPP]
        cross1<FX1, 1>(sim, t[5], lane);
        cross1<FX2, 2>(sre, t[4], lane);             // wire 4 (lane bit 1) [DPP]
        cross1<FX2, 2>(sim, t[4], lane);
        czA(sre); czA(sim);
    }

    // ---- expectations: a_q = sum(re*re_partner) + sum(im*im_partner)
    // (R16-validated per-component sums, merged accumulator -> ONE reduce). ----
    float myp = 0.f;
    {
        float a0 = cross_exp1<FX32>(sre) + cross_exp1<FX32>(sim);   // [LDS]
        float a1 = cross_exp1<FX16>(sre) + cross_exp1<FX16>(sim);   // [LDS]
        float a2 = cross_exp_dpp2<0x141,0x140>(sre) + cross_exp_dpp2<0x141,0x140>(sim);
        float a3 = cross_exp_dpp2<0x141,0x1B >(sre) + cross_exp_dpp2<0x141,0x1B >(sim);
        float a4 = cross_exp1<FX2>(sre) + cross_exp1<FX2>(sim);
        float a5 = cross_exp1<FX1>(sre) + cross_exp1<FX1>(sim);
        float a6 = intra_exp1<8>(sre) + intra_exp1<8>(sim);
        float a7 = intra_exp1<4>(sre) + intra_exp1<4>(sim);
        float a8 = intra_exp1<2>(sre) + intra_exp1<2>(sim);
        float a9 = intra_exp1<1>(sre) + intra_exp1<1>(sim);
        float e0 = wave_reduce(a0);
        float e1 = wave_reduce(a1);
        float e2 = wave_reduce(a2);
        float e3 = wave_reduce(a3);
        float e4 = wave_reduce(a4);
        float e5 = wave_reduce(a5);
        float e6 = wave_reduce(a6);
        float e7 = wave_reduce(a7);
        float e8 = wave_reduce(a8);
        float e9 = wave_reduce(a9);
        myp = (lane == 0) ? e0 : myp;
        myp = (lane == 1) ? e1 : myp;
        myp = (lane == 2) ? e2 : myp;
        myp = (lane == 3) ? e3 : myp;
        myp = (lane == 4) ? e4 : myp;
        myp = (lane == 5) ? e5 : myp;
        myp = (lane == 6) ? e6 : myp;
        myp = (lane == 7) ? e7 : myp;
        myp = (lane == 8) ? e8 : myp;
        myp = (lane == 9) ? e9 : myp;
    }

    // ---- store: one wave owns the full (b,g) output row; no LDS/barrier ----
    if (lane < NQ)
        out[b * (NG * NQ) + g * NQ + lane] = myp * scale2;
}

extern "C" void kernel_launch(void* const* d_in, const int* in_sizes, int n_in,
                              void* d_out, int out_size, void* d_ws, size_t ws_size,
                              hipStream_t stream) {
    const float* noise = (const float*)d_in[0];   // (1024, 10) float32
    const float* qp    = (const float*)d_in[1];   // (4, 6, 10) float32
    float* out = (float*)d_out;                   // (1024, 40) float32

    const int nblocks = NBATCH;                   // 1024 blocks x 4 waves
    qsim_kernel<<<nblocks, 256, 0, stream>>>(noise, qp, out);
}